// Round 1
// baseline (217.351 us; speedup 1.0000x reference)
//
#include <hip/hip_runtime.h>
#include <cstdint>
#include <cstddef>

#define N_  16
#define C_  64
#define H_  224
#define W_  224
#define HW_ (H_ * W_)      // 50176
#define NHW_ (N_ * HW_)    // 802816

typedef unsigned long long u64;

// ---------------------------------------------------------------------------
// ws layout (bytes):
//   [0,      16384) double2 part[64*16]   per-(c,n) partial {sum, sumsq}
//   [16384,  16640) float scale[64]       gamma * inv_std
//   [16640,  16896) float bias[64]        beta - mean*gamma*inv_std
//   [16896,  17152) float alphaf[64]
//   [17152,  21760) u64   wbits[64*9]     weight sign bits packed over C
//   [32768, +6.4MB) u64   abits[16*50176] activation sign bits packed over C
// ---------------------------------------------------------------------------

__global__ void k_stats(const float* __restrict__ x, double2* __restrict__ part) {
    int b = blockIdx.x;          // 0..1023 = (n,c)
    int c = b & 63;
    int n = b >> 6;
    const float4* px = (const float4*)(x + (size_t)(n * 64 + c) * HW_);
    double s = 0.0, ss = 0.0;
    for (int i = threadIdx.x; i < HW_ / 4; i += 256) {
        float4 v = px[i];
        s  += (double)v.x + (double)v.y + (double)v.z + (double)v.w;
        ss += (double)v.x * v.x + (double)v.y * v.y
            + (double)v.z * v.z + (double)v.w * v.w;
    }
    __shared__ double sh_s[256];
    __shared__ double sh_q[256];
    sh_s[threadIdx.x] = s;
    sh_q[threadIdx.x] = ss;
    __syncthreads();
    for (int off = 128; off > 0; off >>= 1) {
        if (threadIdx.x < (unsigned)off) {
            sh_s[threadIdx.x] += sh_s[threadIdx.x + off];
            sh_q[threadIdx.x] += sh_q[threadIdx.x + off];
        }
        __syncthreads();
    }
    if (threadIdx.x == 0) part[c * 16 + n] = make_double2(sh_s[0], sh_q[0]);
}

__global__ void k_finalize(const double2* __restrict__ part,
                           const float* __restrict__ gamma,
                           const float* __restrict__ beta,
                           const float* __restrict__ weight,
                           const float* __restrict__ alpha,
                           float* __restrict__ scale,
                           float* __restrict__ bias,
                           float* __restrict__ alphaf,
                           u64* __restrict__ wbits) {
    int t = threadIdx.x;
    if (t < 64) {
        double s = 0.0, ss = 0.0;
        for (int n = 0; n < 16; ++n) {
            double2 p = part[t * 16 + n];
            s += p.x; ss += p.y;
        }
        double mean = s / (double)NHW_;
        double var  = ss / (double)NHW_ - mean * mean;   // biased, matches x.var
        double inv  = 1.0 / sqrt(var + 1e-5);
        double g    = (double)gamma[t];
        scale[t]  = (float)(g * inv);
        bias[t]   = (float)((double)beta[t] - mean * g * inv);
        alphaf[t] = alpha[t];
    }
    if (t < 576) {
        int o = t / 9, k = t % 9;
        u64 b = 0;
        for (int i = 0; i < 64; ++i) {
            float wv = weight[(size_t)(o * 64 + i) * 9 + k];
            if (wv < 0.0f) b |= (1ull << i);   // bit=1 <=> sign -1 ; w>=0 -> +1
        }
        wbits[t] = b;
    }
}

__global__ void k_binpack(const float* __restrict__ x,
                          const float* __restrict__ scale,
                          const float* __restrict__ bias,
                          u64* __restrict__ abits) {
    __shared__ float s_scale[64];
    __shared__ float s_bias[64];
    if (threadIdx.x < 64) {
        s_scale[threadIdx.x] = scale[threadIdx.x];
        s_bias[threadIdx.x]  = bias[threadIdx.x];
    }
    __syncthreads();
    int idx = blockIdx.x * 256 + threadIdx.x;   // 0 .. NHW_-1
    int n = idx / HW_;
    int p = idx - n * HW_;
    const float* px = x + (size_t)n * 64 * HW_ + p;
    u64 word = 0;
#pragma unroll 16
    for (int c = 0; c < 64; ++c) {
        float v = px[(size_t)c * HW_];
        float t = fmaf(v, s_scale[c], s_bias[c]);
        if (t < 0.0f) word |= (1ull << c);      // out>=0 -> +1 -> bit 0
    }
    abits[idx] = word;
}

__global__ void k_conv(const float* __restrict__ x,
                       const u64* __restrict__ abits,
                       const u64* __restrict__ wbits,
                       const float* __restrict__ alphaf,
                       float* __restrict__ out) {
    int idx = blockIdx.x * 256 + threadIdx.x;   // quad index
    int wq = idx % 56;
    int t1 = idx / 56;
    int h  = t1 % 224;
    int t2 = t1 / 224;
    int o  = t2 & 63;
    int n  = t2 >> 6;
    int w0 = wq * 4;

    const u64* An = abits + (size_t)n * HW_;
    const u64* wb = wbits + o * 9;
    bool v0 = (w0 - 1 >= 0);      // false only for wq==0
    bool v5 = (w0 + 4 <= 223);    // false only for wq==55

    int acc0 = 0, acc1 = 0, acc2 = 0, acc3 = 0;
#pragma unroll
    for (int dh = 0; dh < 3; ++dh) {
        int r = h - 1 + dh;
        if (r < 0 || r >= 224) continue;
        const u64* row = An + r * 224;
        u64 a0 = v0 ? row[w0 - 1] : 0ull;
        u64 a1 = row[w0 + 0];
        u64 a2 = row[w0 + 1];
        u64 a3 = row[w0 + 2];
        u64 a4 = row[w0 + 3];
        u64 a5 = v5 ? row[w0 + 4] : 0ull;
        u64 wv0 = wb[dh * 3 + 0];
        u64 wv1 = wb[dh * 3 + 1];
        u64 wv2 = wb[dh * 3 + 2];
        // output k uses columns a[k+0], a[k+1], a[k+2] against wv0,wv1,wv2
        acc0 += (v0 ? (64 - 2 * __popcll(a0 ^ wv0)) : 0)
              + (64 - 2 * __popcll(a1 ^ wv1))
              + (64 - 2 * __popcll(a2 ^ wv2));
        acc1 += (64 - 2 * __popcll(a1 ^ wv0))
              + (64 - 2 * __popcll(a2 ^ wv1))
              + (64 - 2 * __popcll(a3 ^ wv2));
        acc2 += (64 - 2 * __popcll(a2 ^ wv0))
              + (64 - 2 * __popcll(a3 ^ wv1))
              + (64 - 2 * __popcll(a4 ^ wv2));
        acc3 += (64 - 2 * __popcll(a3 ^ wv0))
              + (64 - 2 * __popcll(a4 ^ wv1))
              + (v5 ? (64 - 2 * __popcll(a5 ^ wv2)) : 0);
    }

    size_t xoff = (size_t)(n * 64 + o) * HW_ + (size_t)h * 224 + w0;
    float4 xr = *(const float4*)(x + xoff);
    float al = alphaf[o];
    float4 yo;
    yo.x = fmaf(al, (float)acc0, xr.x);
    yo.y = fmaf(al, (float)acc1, xr.y);
    yo.z = fmaf(al, (float)acc2, xr.z);
    yo.w = fmaf(al, (float)acc3, xr.w);
    *(float4*)(out + xoff) = yo;
}

extern "C" void kernel_launch(void* const* d_in, const int* in_sizes, int n_in,
                              void* d_out, int out_size, void* d_ws, size_t ws_size,
                              hipStream_t stream) {
    const float* x      = (const float*)d_in[0];
    const float* gamma  = (const float*)d_in[1];
    const float* beta   = (const float*)d_in[2];
    const float* weight = (const float*)d_in[3];
    const float* alpha  = (const float*)d_in[4];
    float* out = (float*)d_out;

    char* ws = (char*)d_ws;
    double2* part  = (double2*)(ws + 0);
    float*   scale = (float*)(ws + 16384);
    float*   bias  = (float*)(ws + 16640);
    float*   alphaf= (float*)(ws + 16896);
    u64*     wbits = (u64*)(ws + 17152);
    u64*     abits = (u64*)(ws + 32768);

    k_stats   <<<N_ * C_, 256, 0, stream>>>(x, part);
    k_finalize<<<1, 576, 0, stream>>>(part, gamma, beta, weight, alpha,
                                      scale, bias, alphaf, wbits);
    k_binpack <<<NHW_ / 256, 256, 0, stream>>>(x, scale, bias, abits);
    k_conv    <<<(N_ * C_ * H_ * (W_ / 4)) / 256, 256, 0, stream>>>(
                  x, abits, wbits, alphaf, out);
}

// Round 2
// 180.502 us; speedup vs baseline: 1.2041x; 1.2041x over previous
//
#include <hip/hip_runtime.h>
#include <cstdint>
#include <cstddef>

#define N_  16
#define C_  64
#define H_  224
#define W_  224
#define HW_ (H_ * W_)      // 50176
#define NHW_ (N_ * HW_)    // 802816

typedef unsigned long long u64;

// ---------------------------------------------------------------------------
// ws layout (bytes):
//   [0,      16384) double2 part[64*16]   per-(c,n) partial {sum, sumsq}
//   [16384,  16640) float scale[64]
//   [16640,  16896) float bias[64]
//   [16896,  17152) float alphaf[64]
//   [17152,  21760) u64   wbits[64*9]
//   [32768, +6.4MB) u64   abits[16*50176]
// ---------------------------------------------------------------------------

__global__ void k_stats(const float* __restrict__ x, double2* __restrict__ part) {
    int b = blockIdx.x;          // (n,c)
    int c = b & 63;
    int n = b >> 6;
    const float4* px = (const float4*)(x + (size_t)(n * 64 + c) * HW_);
    double s = 0.0, ss = 0.0;
    for (int i = threadIdx.x; i < HW_ / 4; i += 256) {
        float4 v = px[i];
        s  += (double)v.x + (double)v.y + (double)v.z + (double)v.w;
        ss += (double)v.x * v.x + (double)v.y * v.y
            + (double)v.z * v.z + (double)v.w * v.w;
    }
    __shared__ double sh_s[256];
    __shared__ double sh_q[256];
    sh_s[threadIdx.x] = s;
    sh_q[threadIdx.x] = ss;
    __syncthreads();
    for (int off = 128; off > 0; off >>= 1) {
        if (threadIdx.x < (unsigned)off) {
            sh_s[threadIdx.x] += sh_s[threadIdx.x + off];
            sh_q[threadIdx.x] += sh_q[threadIdx.x + off];
        }
        __syncthreads();
    }
    if (threadIdx.x == 0) part[c * 16 + n] = make_double2(sh_s[0], sh_q[0]);
}

__global__ void k_finalize(const double2* __restrict__ part,
                           const float* __restrict__ gamma,
                           const float* __restrict__ beta,
                           const float* __restrict__ weight,
                           const float* __restrict__ alpha,
                           float* __restrict__ scale,
                           float* __restrict__ bias,
                           float* __restrict__ alphaf,
                           u64* __restrict__ wbits) {
    int t = threadIdx.x;
    if (t < 64) {
        double s = 0.0, ss = 0.0;
        for (int n = 0; n < 16; ++n) {
            double2 p = part[t * 16 + n];
            s += p.x; ss += p.y;
        }
        double mean = s / (double)NHW_;
        double var  = ss / (double)NHW_ - mean * mean;
        double inv  = 1.0 / sqrt(var + 1e-5);
        double g    = (double)gamma[t];
        scale[t]  = (float)(g * inv);
        bias[t]   = (float)((double)beta[t] - mean * g * inv);
        alphaf[t] = alpha[t];
    }
    if (t < 576) {
        int o = t / 9, k = t % 9;
        u64 b = 0;
        for (int i = 0; i < 64; ++i) {
            float wv = weight[(size_t)(o * 64 + i) * 9 + k];
            if (wv < 0.0f) b |= (1ull << i);
        }
        wbits[t] = b;
    }
}

__global__ void k_binpack(const float* __restrict__ x,
                          const float* __restrict__ scale,
                          const float* __restrict__ bias,
                          u64* __restrict__ abits) {
    __shared__ float s_scale[64];
    __shared__ float s_bias[64];
    if (threadIdx.x < 64) {
        s_scale[threadIdx.x] = scale[threadIdx.x];
        s_bias[threadIdx.x]  = bias[threadIdx.x];
    }
    __syncthreads();
    int idx = blockIdx.x * 256 + threadIdx.x;
    int n = idx / HW_;
    int p = idx - n * HW_;
    const float* px = x + (size_t)n * 64 * HW_ + p;
    u64 word = 0;
#pragma unroll 16
    for (int c = 0; c < 64; ++c) {
        float v = px[(size_t)c * HW_];
        float t = fmaf(v, s_scale[c], s_bias[c]);
        if (t < 0.0f) word |= (1ull << c);
    }
    abits[idx] = word;
}

struct Row { u64 a[6]; };

__device__ __forceinline__ void load_row(const u64* __restrict__ p,
                                         int om1, int o5, bool v0, bool v5,
                                         Row& r) {
    ulonglong2 x01 = *(const ulonglong2*)(p);
    ulonglong2 x23 = *(const ulonglong2*)(p + 2);
    u64 am = p[om1];
    u64 ap = p[o5];
    r.a[0] = v0 ? am : 0ull;
    r.a[1] = x01.x; r.a[2] = x01.y; r.a[3] = x23.x; r.a[4] = x23.y;
    r.a[5] = v5 ? ap : 0ull;
}

// popc-sum over 3 taps for 4 outputs; bases folded for edge columns
#define RACC(R, dh) do { \
    s0 += (int)(__popcll(R.a[0] ^ Wv9[3*dh+0]) + __popcll(R.a[1] ^ Wv9[3*dh+1]) + __popcll(R.a[2] ^ Wv9[3*dh+2])); \
    s1 += (int)(__popcll(R.a[1] ^ Wv9[3*dh+0]) + __popcll(R.a[2] ^ Wv9[3*dh+1]) + __popcll(R.a[3] ^ Wv9[3*dh+2])); \
    s2 += (int)(__popcll(R.a[2] ^ Wv9[3*dh+0]) + __popcll(R.a[3] ^ Wv9[3*dh+1]) + __popcll(R.a[4] ^ Wv9[3*dh+2])); \
    s3 += (int)(__popcll(R.a[3] ^ Wv9[3*dh+0]) + __popcll(R.a[4] ^ Wv9[3*dh+1]) + __popcll(R.a[5] ^ Wv9[3*dh+2])); \
    B0 += b0c[dh]; B3 += b3c[dh]; \
  } while (0)

__global__ void k_conv(const float* __restrict__ x,
                       const u64* __restrict__ abits,
                       const u64* __restrict__ wbits,
                       const float* __restrict__ alphaf,
                       float* __restrict__ out) {
    const int lane = threadIdx.x & 63;
    const int wid  = threadIdx.x >> 6;
    if (lane >= 56) return;
    const int no = blockIdx.y;           // n*64 + o  (o wave-uniform)
    const int o  = no & 63;
    const int n  = no >> 6;
    const int h0 = (blockIdx.x * 4 + wid) * 8;   // 8 rows per wave
    const int w0 = lane * 4;
    const bool v0 = (lane != 0);
    const bool v5 = (lane != 55);
    const int om1 = v0 ? -1 : 0;         // halo offsets, clamped in-bounds
    const int o5  = v5 ? 4 : 3;

    u64 Wv9[9];
    const u64* wb = wbits + o * 9;
#pragma unroll
    for (int k = 0; k < 9; ++k) Wv9[k] = wb[k];

    int b0c[3], b3c[3];
#pragma unroll
    for (int d = 0; d < 3; ++d) {
        b0c[d] = v0 ? 192 : 128 + 2 * (int)__popcll(Wv9[3*d+0]);
        b3c[d] = v5 ? 192 : 128 + 2 * (int)__popcll(Wv9[3*d+2]);
    }
    const float al = alphaf[o];

    const u64* An = abits + (size_t)n * HW_;
    Row rows[3];
#pragma unroll
    for (int k = 0; k < 6; ++k) rows[0].a[k] = 0ull;

    if (h0 > 0) load_row(An + (size_t)(h0 - 1) * 224 + w0, om1, o5, v0, v5, rows[0]);
    load_row(An + (size_t)h0 * 224 + w0, om1, o5, v0, v5, rows[1]);

    size_t xoff = (size_t)no * HW_ + (size_t)h0 * 224 + w0;

#pragma unroll
    for (int hh = 0; hh < 8; ++hh) {
        const int h = h0 + hh;
        Row& Rm = rows[(hh + 0) % 3];
        Row& R0 = rows[(hh + 1) % 3];
        Row& Rp = rows[(hh + 2) % 3];
        if (h < 223) load_row(An + (size_t)(h + 1) * 224 + w0, om1, o5, v0, v5, Rp);
        int s0 = 0, s1 = 0, s2 = 0, s3 = 0, B0 = 0, B3 = 0, nb = 0;
        if (h > 0)   { RACC(Rm, 0); nb += 192; }
        { RACC(R0, 1); nb += 192; }
        if (h < 223) { RACC(Rp, 2); nb += 192; }
        float4 xr = *(const float4*)(x + xoff);
        float4 yo;
        yo.x = fmaf(al, (float)(B0 - 2 * s0), xr.x);
        yo.y = fmaf(al, (float)(nb - 2 * s1), xr.y);
        yo.z = fmaf(al, (float)(nb - 2 * s2), xr.z);
        yo.w = fmaf(al, (float)(B3 - 2 * s3), xr.w);
        *(float4*)(out + xoff) = yo;
        xoff += 224;
    }
}

extern "C" void kernel_launch(void* const* d_in, const int* in_sizes, int n_in,
                              void* d_out, int out_size, void* d_ws, size_t ws_size,
                              hipStream_t stream) {
    const float* x      = (const float*)d_in[0];
    const float* gamma  = (const float*)d_in[1];
    const float* beta   = (const float*)d_in[2];
    const float* weight = (const float*)d_in[3];
    const float* alpha  = (const float*)d_in[4];
    float* out = (float*)d_out;

    char* ws = (char*)d_ws;
    double2* part  = (double2*)(ws + 0);
    float*   scale = (float*)(ws + 16384);
    float*   bias  = (float*)(ws + 16640);
    float*   alphaf= (float*)(ws + 16896);
    u64*     wbits = (u64*)(ws + 17152);
    u64*     abits = (u64*)(ws + 32768);

    k_stats   <<<N_ * C_, 256, 0, stream>>>(x, part);
    k_finalize<<<1, 576, 0, stream>>>(part, gamma, beta, weight, alpha,
                                      scale, bias, alphaf, wbits);
    k_binpack <<<NHW_ / 256, 256, 0, stream>>>(x, scale, bias, abits);
    k_conv    <<<dim3(7, 1024), 256, 0, stream>>>(x, abits, wbits, alphaf, out);
}

// Round 4
// 156.186 us; speedup vs baseline: 1.3916x; 1.1557x over previous
//
#include <hip/hip_runtime.h>
#include <cstdint>
#include <cstddef>

#define N_  16
#define C_  64
#define H_  224
#define W_  224
#define HW_ (H_ * W_)      // 50176
#define NHW_ (N_ * HW_)    // 802816

typedef unsigned long long u64;
typedef float f32x4 __attribute__((ext_vector_type(4)));

// ---------------------------------------------------------------------------
// ws layout (bytes):
//   [0,      16384) double2 part[64*16]   per-(c,n) partial {sum, sumsq}
//   [16384,  16640) float scale[64]
//   [16640,  16896) float bias[64]
//   [16896,  17152) float alphaf[64]
//   [17152,  21760) u64   wbits[64*9]
//   [32768, +6.4MB) u64   abits[16*50176]
// ---------------------------------------------------------------------------

__global__ void k_stats(const float* __restrict__ x, double2* __restrict__ part) {
    int b = blockIdx.x;          // (n,c)
    int c = b & 63;
    int n = b >> 6;
    const float4* px = (const float4*)(x + (size_t)(n * 64 + c) * HW_);
    double s = 0.0, ss = 0.0;
    for (int i = threadIdx.x; i < HW_ / 4; i += 256) {
        float4 v = px[i];
        s  += (double)v.x + (double)v.y + (double)v.z + (double)v.w;
        ss += (double)v.x * v.x + (double)v.y * v.y
            + (double)v.z * v.z + (double)v.w * v.w;
    }
    __shared__ double sh_s[256];
    __shared__ double sh_q[256];
    sh_s[threadIdx.x] = s;
    sh_q[threadIdx.x] = ss;
    __syncthreads();
    for (int off = 128; off > 0; off >>= 1) {
        if (threadIdx.x < (unsigned)off) {
            sh_s[threadIdx.x] += sh_s[threadIdx.x + off];
            sh_q[threadIdx.x] += sh_q[threadIdx.x + off];
        }
        __syncthreads();
    }
    if (threadIdx.x == 0) part[c * 16 + n] = make_double2(sh_s[0], sh_q[0]);
}

__global__ void k_finalize(const double2* __restrict__ part,
                           const float* __restrict__ gamma,
                           const float* __restrict__ beta,
                           const float* __restrict__ weight,
                           const float* __restrict__ alpha,
                           float* __restrict__ scale,
                           float* __restrict__ bias,
                           float* __restrict__ alphaf,
                           u64* __restrict__ wbits) {
    int t = threadIdx.x;
    if (t < 64) {
        double s = 0.0, ss = 0.0;
        for (int n = 0; n < 16; ++n) {
            double2 p = part[t * 16 + n];
            s += p.x; ss += p.y;
        }
        double mean = s / (double)NHW_;
        double var  = ss / (double)NHW_ - mean * mean;
        double inv  = 1.0 / sqrt(var + 1e-5);
        double g    = (double)gamma[t];
        scale[t]  = (float)(g * inv);
        bias[t]   = (float)((double)beta[t] - mean * g * inv);
        alphaf[t] = alpha[t];
    }
    if (t < 576) {
        int o = t / 9, k = t % 9;
        u64 b = 0;
        for (int i = 0; i < 64; ++i) {
            float wv = weight[(size_t)(o * 64 + i) * 9 + k];
            if (wv < 0.0f) b |= (1ull << i);
        }
        wbits[t] = b;
    }
}

// one thread = 4 consecutive spatial positions, all 64 channels
__global__ void k_binpack(const float* __restrict__ x,
                          const float* __restrict__ scale,
                          const float* __restrict__ bias,
                          u64* __restrict__ abits) {
    __shared__ float s_scale[64];
    __shared__ float s_bias[64];
    if (threadIdx.x < 64) {
        s_scale[threadIdx.x] = scale[threadIdx.x];
        s_bias[threadIdx.x]  = bias[threadIdx.x];
    }
    __syncthreads();
    int q  = blockIdx.x * 256 + threadIdx.x;   // quad id 0..200703
    int n  = q / (HW_ / 4);
    int p4 = q - n * (HW_ / 4);
    const float* px = x + (size_t)n * 64 * HW_ + (size_t)p4 * 4;

    unsigned lo0 = 0, lo1 = 0, lo2 = 0, lo3 = 0;
    unsigned hi0 = 0, hi1 = 0, hi2 = 0, hi3 = 0;
#pragma unroll 8
    for (int c = 0; c < 32; ++c) {
        float4 v = *(const float4*)(px + (size_t)c * HW_);
        float sc = s_scale[c], bi = s_bias[c];
        lo0 |= (fmaf(v.x, sc, bi) < 0.0f ? 1u : 0u) << c;
        lo1 |= (fmaf(v.y, sc, bi) < 0.0f ? 1u : 0u) << c;
        lo2 |= (fmaf(v.z, sc, bi) < 0.0f ? 1u : 0u) << c;
        lo3 |= (fmaf(v.w, sc, bi) < 0.0f ? 1u : 0u) << c;
    }
#pragma unroll 8
    for (int c = 32; c < 64; ++c) {
        float4 v = *(const float4*)(px + (size_t)c * HW_);
        float sc = s_scale[c], bi = s_bias[c];
        hi0 |= (fmaf(v.x, sc, bi) < 0.0f ? 1u : 0u) << (c - 32);
        hi1 |= (fmaf(v.y, sc, bi) < 0.0f ? 1u : 0u) << (c - 32);
        hi2 |= (fmaf(v.z, sc, bi) < 0.0f ? 1u : 0u) << (c - 32);
        hi3 |= (fmaf(v.w, sc, bi) < 0.0f ? 1u : 0u) << (c - 32);
    }
    u64* dst = abits + (size_t)q * 4;
    ulonglong2 w01, w23;
    w01.x = (u64)lo0 | ((u64)hi0 << 32);
    w01.y = (u64)lo1 | ((u64)hi1 << 32);
    w23.x = (u64)lo2 | ((u64)hi2 << 32);
    w23.y = (u64)lo3 | ((u64)hi3 << 32);
    *(ulonglong2*)(dst)     = w01;
    *(ulonglong2*)(dst + 2) = w23;
}

struct Row { u64 a[6]; };

__device__ __forceinline__ void load_row(const u64* __restrict__ p,
                                         int om1, int o5, bool v0, bool v5,
                                         Row& r) {
    ulonglong2 x01 = *(const ulonglong2*)(p);
    ulonglong2 x23 = *(const ulonglong2*)(p + 2);
    u64 am = p[om1];
    u64 ap = p[o5];
    r.a[0] = v0 ? am : 0ull;
    r.a[1] = x01.x; r.a[2] = x01.y; r.a[3] = x23.x; r.a[4] = x23.y;
    r.a[5] = v5 ? ap : 0ull;
}

#define RACC(R, dh) do { \
    s0 += (int)(__popcll(R.a[0] ^ Wv9[3*dh+0]) + __popcll(R.a[1] ^ Wv9[3*dh+1]) + __popcll(R.a[2] ^ Wv9[3*dh+2])); \
    s1 += (int)(__popcll(R.a[1] ^ Wv9[3*dh+0]) + __popcll(R.a[2] ^ Wv9[3*dh+1]) + __popcll(R.a[3] ^ Wv9[3*dh+2])); \
    s2 += (int)(__popcll(R.a[2] ^ Wv9[3*dh+0]) + __popcll(R.a[3] ^ Wv9[3*dh+1]) + __popcll(R.a[4] ^ Wv9[3*dh+2])); \
    s3 += (int)(__popcll(R.a[3] ^ Wv9[3*dh+0]) + __popcll(R.a[4] ^ Wv9[3*dh+1]) + __popcll(R.a[5] ^ Wv9[3*dh+2])); \
    B0 += b0c[dh]; B3 += b3c[dh]; \
  } while (0)

__global__ void k_conv(const float* __restrict__ x,
                       const u64* __restrict__ abits,
                       const u64* __restrict__ wbits,
                       const float* __restrict__ alphaf,
                       float* __restrict__ out) {
    const int lane = threadIdx.x & 63;
    const int wid  = threadIdx.x >> 6;
    if (lane >= 56) return;
    const int no = blockIdx.y;           // n*64 + o  (o wave-uniform)
    const int o  = no & 63;
    const int n  = no >> 6;
    const int h0 = (blockIdx.x * 4 + wid) * 8;   // 8 rows per wave
    const int w0 = lane * 4;
    const bool v0 = (lane != 0);
    const bool v5 = (lane != 55);
    const int om1 = v0 ? -1 : 0;
    const int o5  = v5 ? 4 : 3;

    u64 Wv9[9];
    const u64* wb = wbits + o * 9;      // uniform address -> s_load
#pragma unroll
    for (int k = 0; k < 9; ++k) Wv9[k] = wb[k];

    int b0c[3], b3c[3];
#pragma unroll
    for (int d = 0; d < 3; ++d) {
        b0c[d] = v0 ? 192 : 128 + 2 * (int)__popcll(Wv9[3*d+0]);
        b3c[d] = v5 ? 192 : 128 + 2 * (int)__popcll(Wv9[3*d+2]);
    }
    const float al = alphaf[o];

    const u64* An = abits + (size_t)n * HW_;
    // ring of 4 row windows; slot(k) = k&3 where k = (row - h0) + 1
    Row R[4];
#pragma unroll
    for (int k = 0; k < 6; ++k) R[0].a[k] = 0ull;

    if (h0 > 0) load_row(An + (size_t)(h0 - 1) * 224 + w0, om1, o5, v0, v5, R[0]);
    load_row(An + (size_t)h0 * 224 + w0, om1, o5, v0, v5, R[1]);
    load_row(An + (size_t)(h0 + 1) * 224 + w0, om1, o5, v0, v5, R[2]);

    size_t xoff = (size_t)no * HW_ + (size_t)h0 * 224 + w0;

#pragma unroll
    for (int hh = 0; hh < 8; ++hh) {
        const int h = h0 + hh;
        // prefetch row h+2 one iteration ahead of its use
        if (hh < 7 && h + 2 <= 223)
            load_row(An + (size_t)(h + 2) * 224 + w0, om1, o5, v0, v5,
                     R[(hh + 3) & 3]);
        float4 xr = *(const float4*)(x + xoff);   // issue residual load early
        Row& Rm = R[(hh + 0) & 3];
        Row& R0 = R[(hh + 1) & 3];
        Row& Rp = R[(hh + 2) & 3];
        int s0 = 0, s1 = 0, s2 = 0, s3 = 0, B0 = 0, B3 = 0, nb = 0;
        if (h > 0)   { RACC(Rm, 0); nb += 192; }
        { RACC(R0, 1); nb += 192; }
        if (h < 223) { RACC(Rp, 2); nb += 192; }
        f32x4 yo;
        yo.x = fmaf(al, (float)(B0 - 2 * s0), xr.x);
        yo.y = fmaf(al, (float)(nb - 2 * s1), xr.y);
        yo.z = fmaf(al, (float)(nb - 2 * s2), xr.z);
        yo.w = fmaf(al, (float)(B3 - 2 * s3), xr.w);
        __builtin_nontemporal_store(yo, (f32x4*)(out + xoff));
        xoff += 224;
    }
}

extern "C" void kernel_launch(void* const* d_in, const int* in_sizes, int n_in,
                              void* d_out, int out_size, void* d_ws, size_t ws_size,
                              hipStream_t stream) {
    const float* x      = (const float*)d_in[0];
    const float* gamma  = (const float*)d_in[1];
    const float* beta   = (const float*)d_in[2];
    const float* weight = (const float*)d_in[3];
    const float* alpha  = (const float*)d_in[4];
    float* out = (float*)d_out;

    char* ws = (char*)d_ws;
    double2* part  = (double2*)(ws + 0);
    float*   scale = (float*)(ws + 16384);
    float*   bias  = (float*)(ws + 16640);
    float*   alphaf= (float*)(ws + 16896);
    u64*     wbits = (u64*)(ws + 17152);
    u64*     abits = (u64*)(ws + 32768);

    k_stats   <<<N_ * C_, 256, 0, stream>>>(x, part);
    k_finalize<<<1, 576, 0, stream>>>(part, gamma, beta, weight, alpha,
                                      scale, bias, alphaf, wbits);
    k_binpack <<<(NHW_ / 4) / 256, 256, 0, stream>>>(x, scale, bias, abits);
    k_conv    <<<dim3(7, 1024), 256, 0, stream>>>(x, abits, wbits, alphaf, out);
}